// Round 10
// baseline (17005.260 us; speedup 1.0000x reference)
//
#include <hip/hip_runtime.h>
#include <math.h>

#define ND 64
#define PAD 65
#define NN 4096
#define NB 8192

// ws layout (floats)
#define OFF_MEANPART ((size_t)0)        // 32*4096
#define OFF_MEANA    ((size_t)131072)
#define OFF_S        ((size_t)135168)
#define OFF_SI       ((size_t)139264)
#define OFF_SS       ((size_t)143360)
#define OFF_TBAR     ((size_t)147456)
#define OFF_MI       ((size_t)151552)
#define OFF_P        ((size_t)155648)
#define OFF_VARPART  ((size_t)155712)   // 2048 slots
#define OFF_LAM      ((size_t)157760)   // NB*ND: lg (stage2 phase) then sigma
#define OFF_TPART    ((size_t)682048)   // G2*4096 per-block partials

#define G2_BLOCKS 2048
#define G3_BLOCKS 2048

// ---------------------------------------------------------------------------
__device__ __forceinline__ float bperm_f(int pa, float x) {
  return __builtin_bit_cast(float,
      __builtin_amdgcn_ds_bpermute(pa, __builtin_bit_cast(int, x)));
}

// ---------------------------------------------------------------------------
// One-sided Jacobi, single wave per matrix, lane = column, w[64] = own column.
// Runtime XOR-tournament loop, ds_bpermute exchange with asm-pinned results
// (no remat double-issue). Wave-synchronous, no barriers. Returns ||w||^2.
// Live set ~145 regs -> fits the 170-VGPR budget of __launch_bounds__(64,3).
// ---------------------------------------------------------------------------
__device__ float jacobi1s64(float (&w)[ND], int lane) {
  float a0 = 0.f, a1 = 0.f, a2 = 0.f, a3 = 0.f;
#pragma unroll
  for (int i = 0; i < ND; i += 4) {
    a0 = fmaf(w[i + 0], w[i + 0], a0);
    a1 = fmaf(w[i + 1], w[i + 1], a1);
    a2 = fmaf(w[i + 2], w[i + 2], a2);
    a3 = fmaf(w[i + 3], w[i + 3], a3);
  }
  float g = (a0 + a1) + (a2 + a3);

  for (int sweep = 0; sweep < 18; ++sweep) {
    bool any = false;
    for (int r = 1; r < ND; ++r) {
      int pa = (lane ^ r) << 2;
      float v[ND + 1];  // v[64] = partner's g
#pragma unroll
      for (int i = 0; i <= ND; ++i) {
        float t = bperm_f(pa, (i < ND) ? w[i] : g);
        asm volatile("" : "+v"(t));  // pin: keep live, never re-issue
        v[i] = t;
      }
      float gv = v[ND];
      float b0 = 0.f, b1 = 0.f, b2 = 0.f, b3 = 0.f;
#pragma unroll
      for (int i = 0; i < ND; i += 4) {
        b0 = fmaf(w[i + 0], v[i + 0], b0);
        b1 = fmaf(w[i + 1], v[i + 1], b1);
        b2 = fmaf(w[i + 2], v[i + 2], b2);
        b3 = fmaf(w[i + 3], v[i + 3], b3);
      }
      float apq = (b0 + b1) + (b2 + b3);
      if (apq * apq > 4e-10f * g * gv) {
        int partner = lane ^ r;
        bool amP = lane < partner;
        float app = amP ? g : gv;
        float aqq = amP ? gv : g;
        float tau = (aqq - app) / (2.f * apq);
        float t = 1.f / (fabsf(tau) + sqrtf(1.f + tau * tau));
        t = (tau < 0.f) ? -t : t;
        float c = 1.f / sqrtf(1.f + t * t);
        float s = t * c;
        float s2v = amP ? -s : s;
#pragma unroll
        for (int i = 0; i < ND; ++i) w[i] = fmaf(s2v, v[i], c * w[i]);
        float d = t * apq;
        g = amP ? (g - d) : (g + d);
        any = true;
      }
    }
    if (!__any(any)) break;
  }
  a0 = a1 = a2 = a3 = 0.f;
#pragma unroll
  for (int i = 0; i < ND; i += 4) {
    a0 = fmaf(w[i + 0], w[i + 0], a0);
    a1 = fmaf(w[i + 1], w[i + 1], a1);
    a2 = fmaf(w[i + 2], w[i + 2], a2);
    a3 = fmaf(w[i + 3], w[i + 3], a3);
  }
  return (a0 + a1) + (a2 + a3);
}

// ---------------------------------------------------------------------------
// Wave-private congruence M = q*(x*q), q symmetric; lane = column of M.
// Two-pass staging of x (32 rows at a time, chunk-swizzled) into an 8KB
// wave-private LDS buffer; B in regs; step2 via half-parking B.
// Validated in round 3. No barriers (single wave).
// ---------------------------------------------------------------------------
__device__ __forceinline__ void congruence2(const float* __restrict__ xi,
                                            const float* __restrict__ q,
                                            float* __restrict__ XL, int lane,
                                            float (&w)[ND]) {
  float B[ND];
#pragma unroll
  for (int i = 0; i < ND; ++i) B[i] = 0.f;

  const float* qc = q + lane * ND;  // q[a][lane] = q[lane][a] (symmetric)
  for (int p = 0; p < 2; ++p) {
    // stage rows [32p, 32p+32): 512 float4 chunks, coalesced reads
#pragma unroll
    for (int k = 0; k < 8; ++k) {
      int m = k * 64 + lane;
      float4 rv = ((const float4*)(xi + p * 2048))[m];
      int phys = m ^ ((m >> 4) & 7);
      ((float4*)XL)[phys] = rv;
    }
    // B[r] += sum_a x[a][r] * q[a][lane]   (x symmetric)
    for (int a0 = 0; a0 < 32; ++a0) {
      int a = p * 32 + a0;
      float sa = qc[a];
      int base = a0 * 16, sw = a0 & 7;
#pragma unroll
      for (int k = 0; k < 16; ++k) {
        const float4 c4 = ((const float4*)XL)[base + (k ^ sw)];
        B[4 * k + 0] = fmaf(c4.x, sa, B[4 * k + 0]);
        B[4 * k + 1] = fmaf(c4.y, sa, B[4 * k + 1]);
        B[4 * k + 2] = fmaf(c4.z, sa, B[4 * k + 2]);
        B[4 * k + 3] = fmaf(c4.w, sa, B[4 * k + 3]);
      }
    }
  }
  // step2: w[r] = sum_a q[r][a] * B[a][lane], B parked in halves
#pragma unroll
  for (int i = 0; i < ND; ++i) w[i] = 0.f;
  for (int h = 0; h < 2; ++h) {
#pragma unroll
    for (int j = 0; j < 32; ++j) XL[j * ND + lane] = B[h * 32 + j];
    for (int a0 = 0; a0 < 32; ++a0) {
      float ba = XL[a0 * ND + lane];
      const float* qr = q + (h * 32 + a0) * ND;  // row (uniform -> s_load)
#pragma unroll
      for (int r = 0; r < ND; ++r) w[r] = fmaf(qr[r], ba, w[r]);
    }
  }
}

// ---------------------------------------------------------------------------
// Two-sided LDS Jacobi (256 threads, one 64x64 matrix) for the few singles.
// ---------------------------------------------------------------------------
__device__ void jacobi2s(float (&A)[ND][PAD], float (&V)[ND][PAD], int tid) {
  __shared__ float cs_[32], sn_[32];
  __shared__ int   pp_[32], qq_[32];
  __shared__ int   rotcnt_;
  __shared__ float fro2_;
  __shared__ float red_[4];

  __syncthreads();
  float loc = 0.f;
  for (int e = tid; e < NN; e += 256) { float a = A[e >> 6][e & 63]; loc += a * a; }
  for (int o = 32; o; o >>= 1) loc += __shfl_down(loc, o);
  if ((tid & 63) == 0) red_[tid >> 6] = loc;
  __syncthreads();
  if (tid == 0) fro2_ = red_[0] + red_[1] + red_[2] + red_[3];
  __syncthreads();
  float fro2 = fro2_;

  for (int sweep = 0; sweep < 20; ++sweep) {
    if (tid == 0) rotcnt_ = 0;
    __syncthreads();
    for (int r = 0; r < 63; ++r) {
      if (tid < 32) {
        int p, q;
        if (tid == 0) { p = 63; q = r; }
        else { p = (r + tid) % 63; q = (r + 63 - tid) % 63; }
        if (p > q) { int t0 = p; p = q; q = t0; }
        pp_[tid] = p; qq_[tid] = q;
        float app = A[p][p], aqq = A[q][q], apq = A[p][q];
        float thr = fmaxf(1e-12f * fabsf(app * aqq), 1e-14f * fro2);
        float c = 1.f, s = 0.f;
        if (apq * apq > thr) {
          float tau = (aqq - app) / (2.f * apq);
          float t = 1.f / (fabsf(tau) + sqrtf(1.f + tau * tau));
          t = (tau < 0.f) ? -t : t;
          c = 1.f / sqrtf(1.f + t * t);
          s = t * c;
          atomicAdd(&rotcnt_, 1);
        }
        cs_[tid] = c; sn_[tid] = s;
      }
      __syncthreads();
      for (int t = tid; t < 2048; t += 256) {
        int k = t >> 6, j = t & 63;
        int p = pp_[k], q = qq_[k]; float c = cs_[k], s = sn_[k];
        float ap = A[p][j], aq = A[q][j];
        A[p][j] = c * ap - s * aq;
        A[q][j] = s * ap + c * aq;
      }
      __syncthreads();
      for (int t = tid; t < 4096; t += 256) {
        int k = (t >> 6) & 31, j = t & 63;
        int p = pp_[k], q = qq_[k]; float c = cs_[k], s = sn_[k];
        if (t < 2048) {
          float ap = A[j][p], aq = A[j][q];
          A[j][p] = c * ap - s * aq;
          A[j][q] = s * ap + c * aq;
        } else {
          float vp = V[j][p], vq = V[j][q];
          V[j][p] = c * vp - s * vq;
          V[j][q] = s * vp + c * vq;
        }
      }
      __syncthreads();
    }
    int rc = rotcnt_;
    __syncthreads();
    if (rc == 0) break;
  }
}

__device__ void recon_write(const float (&V)[ND][PAD], const float* f, float* g,
                            int c, int wq) {
  float acc[16];
#pragma unroll
  for (int k = 0; k < 16; ++k) acc[k] = 0.f;
  for (int j = 0; j < ND; ++j) {
    float m = f[j] * V[c][j];
#pragma unroll
    for (int k = 0; k < 16; ++k) acc[k] = fmaf(V[wq + 4 * k][j], m, acc[k]);
  }
#pragma unroll
  for (int k = 0; k < 16; ++k) g[(wq + 4 * k) * ND + c] = acc[k];
}

// ---------------------------------------------------------------------------
// Kernels
// ---------------------------------------------------------------------------
__global__ __launch_bounds__(256) void k_mean_part(const float* __restrict__ x,
                                                   float* __restrict__ part) {
  int e = blockIdx.x * 256 + threadIdx.x;
  int chunk = blockIdx.y;
  const float* px = x + (size_t)chunk * 256 * NN + e;
  float s = 0.f;
  for (int i = 0; i < 256; ++i) s += px[(size_t)i * NN];
  part[(size_t)chunk * NN + e] = s;
}

__global__ __launch_bounds__(256) void k_mean_final(const float* __restrict__ part,
                                                    float* __restrict__ meanA) {
  int e = blockIdx.x * 256 + threadIdx.x;
  float s = 0.f;
  for (int c = 0; c < 32; ++c) s += part[(size_t)c * NN + e];
  meanA[e] = s * (1.f / (float)NB);
}

__global__ __launch_bounds__(256) void k_prep1(const float* __restrict__ meanA,
                                               const float* __restrict__ shift,
                                               float* __restrict__ s_out,
                                               float* __restrict__ si_out,
                                               float* __restrict__ ss_out) {
  __shared__ float A[ND][PAD], V[ND][PAD];
  __shared__ float f1[ND], f2[ND];
  int tid = threadIdx.x;
  const float* src = (blockIdx.x == 0) ? meanA : shift;
  for (int e = tid; e < NN; e += 256) A[e >> 6][e & 63] = src[e];
  for (int e = tid; e < NN; e += 256) V[e >> 6][e & 63] = ((e >> 6) == (e & 63)) ? 1.f : 0.f;
  jacobi2s(A, V, tid);
  if (tid < ND) {
    float wv = fmaxf(A[tid][tid], 1e-30f);
    f1[tid] = sqrtf(wv);
    f2[tid] = 1.f / sqrtf(wv);
  }
  __syncthreads();
  int c = tid & 63, wq = tid >> 6;
  if (blockIdx.x == 0) {
    recon_write(V, f1, s_out, c, wq);
    recon_write(V, f2, si_out, c, wq);
  } else {
    recon_write(V, f1, ss_out, c, wq);
  }
}

// jacobi-only: M = si*x_i*si eigh -> write U^T (row j = u_j) and log(lambda).
__global__ __launch_bounds__(64, 3) void k_stage2jac(const float* __restrict__ x,
                                                     const float* __restrict__ si,
                                                     float* __restrict__ uout,
                                                     float* __restrict__ lgout,
                                                     int G2) {
  __shared__ float XL[2048];
  int lane = threadIdx.x;
  for (int i = blockIdx.x; i < NB; i += G2) {
    float w[ND];
    congruence2(x + (size_t)i * NN, si, XL, lane, w);
    float s2 = jacobi1s64(w, lane);
    float sig = sqrtf(fmaxf(s2, 1e-38f));
    float inv = 1.f / sig;
    lgout[(size_t)i * ND + lane] = logf(sig);
#pragma unroll
    for (int g2 = 0; g2 < 16; ++g2) {
      float4 u4 = make_float4(w[4 * g2 + 0] * inv, w[4 * g2 + 1] * inv,
                              w[4 * g2 + 2] * inv, w[4 * g2 + 3] * inv);
      *(float4*)(uout + (size_t)i * NN + lane * ND + g2 * 4) = u4;
    }
  }
}

// tangent partials: tPart[bid] = sum_{i in stride} U_i^T diag(lg_i) U_i ... i.e.
// t[r][c] = sum_j lg[j] * Ut[j][r] * Ut[j][c]
__global__ __launch_bounds__(256) void k_tangent(const float* __restrict__ uin,
                                                 const float* __restrict__ lg,
                                                 float* __restrict__ tPart,
                                                 int G2) {
  __shared__ float Ut[ND][PAD];
  __shared__ float lw[ND];
  int tid = threadIdx.x;
  int c = tid & 63, wq = tid >> 6;
  float acc[16];
#pragma unroll
  for (int k = 0; k < 16; ++k) acc[k] = 0.f;

  for (int i = blockIdx.x; i < NB; i += G2) {
    __syncthreads();
    for (int e = tid; e < NN; e += 256) Ut[e >> 6][e & 63] = uin[(size_t)i * NN + e];
    if (tid < ND) lw[tid] = lg[(size_t)i * ND + tid];
    __syncthreads();
    for (int j = 0; j < ND; ++j) {
      float m = lw[j] * Ut[j][c];
#pragma unroll
      for (int k = 0; k < 16; ++k) acc[k] = fmaf(Ut[j][wq + 4 * k], m, acc[k]);
    }
  }
#pragma unroll
  for (int k = 0; k < 16; ++k)
    tPart[(size_t)blockIdx.x * NN + (wq + 4 * k) * ND + c] = acc[k];
}

__global__ __launch_bounds__(256) void k_reduce_t(const float* __restrict__ tPart,
                                                  float* __restrict__ tbar, int nw) {
  int e = blockIdx.x * 256 + threadIdx.x;
  float s = 0.f;
  for (int b = 0; b < nw; ++b) s += tPart[(size_t)b * NN + e];
  tbar[e] = s * (1.f / (float)NB);
}

__global__ __launch_bounds__(256) void k_prep2(const float* __restrict__ tbar,
                                               const float* __restrict__ s_g,
                                               float* __restrict__ mi_out) {
  __shared__ float A[ND][PAD], V[ND][PAD];
  __shared__ float f1[ND];
  int tid = threadIdx.x;
  int c = tid & 63, wq = tid >> 6;
  for (int e = tid; e < NN; e += 256) A[e >> 6][e & 63] = tbar[e];
  for (int e = tid; e < NN; e += 256) V[e >> 6][e & 63] = ((e >> 6) == (e & 63)) ? 1.f : 0.f;
  jacobi2s(A, V, tid);
  if (tid < ND) f1[tid] = expf(A[tid][tid]);
  __syncthreads();
  {
    float acc[16];
#pragma unroll
    for (int k = 0; k < 16; ++k) acc[k] = 0.f;
    for (int j = 0; j < ND; ++j) {
      float m = f1[j] * V[c][j];
#pragma unroll
      for (int k = 0; k < 16; ++k) acc[k] = fmaf(V[wq + 4 * k][j], m, acc[k]);
    }
    __syncthreads();
#pragma unroll
    for (int k = 0; k < 16; ++k) A[wq + 4 * k][c] = acc[k];
  }
  __syncthreads();
  {
    float acc[16];
#pragma unroll
    for (int k = 0; k < 16; ++k) acc[k] = 0.f;
    for (int a = 0; a < ND; ++a) {
      float ea = A[a][c];
#pragma unroll
      for (int k = 0; k < 16; ++k) acc[k] = fmaf(s_g[(wq + 4 * k) * ND + a], ea, acc[k]);
    }
    __syncthreads();
#pragma unroll
    for (int k = 0; k < 16; ++k) V[wq + 4 * k][c] = acc[k];
  }
  __syncthreads();
  {
    float acc[16];
#pragma unroll
    for (int k = 0; k < 16; ++k) acc[k] = 0.f;
    for (int a = 0; a < ND; ++a) {
      float sa = s_g[a * ND + c];
#pragma unroll
      for (int k = 0; k < 16; ++k) acc[k] = fmaf(V[wq + 4 * k][a], sa, acc[k]);
    }
    __syncthreads();
#pragma unroll
    for (int k = 0; k < 16; ++k) A[wq + 4 * k][c] = acc[k];
  }
  __syncthreads();
  for (int e = tid; e < NN; e += 256) V[e >> 6][e & 63] = ((e >> 6) == (e & 63)) ? 1.f : 0.f;
  jacobi2s(A, V, tid);
  if (tid < ND) f1[tid] = 1.f / sqrtf(fmaxf(A[tid][tid], 1e-30f));
  __syncthreads();
  recon_write(V, f1, mi_out, c, wq);
}

// jacobi-only: M = mi*x_i*mi eigh -> write U^T, sigma, var partials.
__global__ __launch_bounds__(64, 3) void k_stage3jac(const float* __restrict__ x,
                                                     const float* __restrict__ mi,
                                                     float* __restrict__ uout,
                                                     float* __restrict__ lam,
                                                     float* __restrict__ varPart,
                                                     int G3) {
  __shared__ float XL[2048];
  int lane = threadIdx.x;
  float varacc = 0.f;
  for (int i = blockIdx.x; i < NB; i += G3) {
    float w[ND];
    congruence2(x + (size_t)i * NN, mi, XL, lane, w);
    float s2 = jacobi1s64(w, lane);
    float sig = sqrtf(fmaxf(s2, 1e-38f));
    float inv = 1.f / sig;
    lam[(size_t)i * ND + lane] = sig;
    float lg = logf(sig);
    varacc = fmaf(lg, lg, varacc);
#pragma unroll
    for (int g2 = 0; g2 < 16; ++g2) {
      float4 u4 = make_float4(w[4 * g2 + 0] * inv, w[4 * g2 + 1] * inv,
                              w[4 * g2 + 2] * inv, w[4 * g2 + 3] * inv);
      *(float4*)(uout + (size_t)i * NN + lane * ND + g2 * 4) = u4;
    }
  }
  for (int o = 32; o; o >>= 1) varacc += __shfl_down(varacc, o);
  if (lane == 0) varPart[blockIdx.x] = varacc;
}

__global__ __launch_bounds__(64) void k_pfinal(const float* __restrict__ varPart,
                                               const float* __restrict__ scale,
                                               float* __restrict__ pout, int n) {
  int tid = threadIdx.x;
  float s = 0.f;
  for (int i = tid; i < n; i += 64) s += varPart[i];
  for (int o = 32; o; o >>= 1) s += __shfl_down(s, o);
  if (tid == 0) {
    float var = s * (1.f / (float)NB);
    float sd = sqrtf(var);
    pout[0] = scale[0] / (sd + 1e-5f);
  }
}

// out_i = (ss*U_i) diag(lam^p) (ss*U_i)^T, U_i read as U^T rows from uin.
__global__ __launch_bounds__(256) void k_stage5(const float* __restrict__ uin,
                                                const float* __restrict__ ss,
                                                const float* __restrict__ lam,
                                                const float* __restrict__ pws,
                                                float* __restrict__ out) {
  __shared__ float Ut[ND][PAD];   // row j = u_j
  __shared__ float A2[ND][PAD];   // A = ss*U
  __shared__ float lp[ND];
  int tid = threadIdx.x;
  int i = blockIdx.x;
  for (int e = tid; e < NN; e += 256) Ut[e >> 6][e & 63] = uin[(size_t)i * NN + e];
  if (tid < ND) lp[tid] = powf(lam[(size_t)i * ND + tid], pws[0]);
  __syncthreads();
  int c = tid & 63, wq = tid >> 6;
  // A[r][c] = sum_a ss[r][a]*U[a][c]; ss sym -> ss[r][a]=ss[a*64+r]; U[a][c]=Ut[c][a]
  float acc[16];
#pragma unroll
  for (int k = 0; k < 16; ++k) acc[k] = 0.f;
  for (int a = 0; a < ND; ++a) {
    float ua = Ut[c][a];
    const float* ssr = ss + a * ND;
#pragma unroll
    for (int k = 0; k < 16; ++k) acc[k] = fmaf(ssr[wq + 4 * k], ua, acc[k]);
  }
#pragma unroll
  for (int k = 0; k < 16; ++k) A2[wq + 4 * k][c] = acc[k];
  __syncthreads();
  float o2[16];
#pragma unroll
  for (int k = 0; k < 16; ++k) o2[k] = 0.f;
  for (int j = 0; j < ND; ++j) {
    float m = lp[j] * A2[c][j];
#pragma unroll
    for (int k = 0; k < 16; ++k) o2[k] = fmaf(A2[wq + 4 * k][j], m, o2[k]);
  }
#pragma unroll
  for (int k = 0; k < 16; ++k)
    out[(size_t)i * NN + (wq + 4 * k) * ND + c] = o2[k];
}

// ---------------------------------------------------------------------------
extern "C" void kernel_launch(void* const* d_in, const int* in_sizes, int n_in,
                              void* d_out, int out_size, void* d_ws, size_t ws_size,
                              hipStream_t stream) {
  const float* x     = (const float*)d_in[0];
  const float* shift = (const float*)d_in[1];
  const float* scale = (const float*)d_in[2];
  float* out = (float*)d_out;
  float* ws  = (float*)d_ws;
  (void)in_sizes; (void)n_in; (void)out_size;

  size_t wsf = ws_size / 4;
  int G2 = G2_BLOCKS;
  if (OFF_TPART + (size_t)G2 * NN > wsf) {
    size_t avail = (wsf > OFF_TPART) ? (wsf - OFF_TPART) / NN : 1;
    if (avail < 1) avail = 1;
    if (avail < (size_t)G2) G2 = (int)avail;
  }

  k_mean_part<<<dim3(16, 32), 256, 0, stream>>>(x, ws + OFF_MEANPART);
  k_mean_final<<<16, 256, 0, stream>>>(ws + OFF_MEANPART, ws + OFF_MEANA);
  k_prep1<<<2, 256, 0, stream>>>(ws + OFF_MEANA, shift, ws + OFF_S, ws + OFF_SI,
                                 ws + OFF_SS);
  // phase A: eigh(si*x*si) -> U^T in d_out (scratch), lg in LAM
  k_stage2jac<<<G2, 64, 0, stream>>>(x, ws + OFF_SI, out, ws + OFF_LAM, G2);
  k_tangent<<<G2, 256, 0, stream>>>(out, ws + OFF_LAM, ws + OFF_TPART, G2);
  k_reduce_t<<<16, 256, 0, stream>>>(ws + OFF_TPART, ws + OFF_TBAR, G2);
  k_prep2<<<1, 256, 0, stream>>>(ws + OFF_TBAR, ws + OFF_S, ws + OFF_MI);
  // phase B: eigh(mi*x*mi) -> U^T in d_out, sigma in LAM, var partials
  k_stage3jac<<<G3_BLOCKS, 64, 0, stream>>>(x, ws + OFF_MI, out, ws + OFF_LAM,
                                            ws + OFF_VARPART, G3_BLOCKS);
  k_pfinal<<<1, 64, 0, stream>>>(ws + OFF_VARPART, scale, ws + OFF_P, G3_BLOCKS);
  // out_i = (ss*U_i) diag(lam^p) (ss*U_i)^T, in place over d_out
  k_stage5<<<8192, 256, 0, stream>>>(out, ws + OFF_SS, ws + OFF_LAM, ws + OFF_P,
                                     out);
}

// Round 11
// 14800.024 us; speedup vs baseline: 1.1490x; 1.1490x over previous
//
#include <hip/hip_runtime.h>
#include <math.h>

#define ND 64
#define PAD 65
#define NN 4096
#define NB 8192

// ws layout (floats)
#define OFF_MEANPART ((size_t)0)        // 32*4096
#define OFF_MEANA    ((size_t)131072)
#define OFF_S        ((size_t)135168)
#define OFF_SI       ((size_t)139264)
#define OFF_SS       ((size_t)143360)
#define OFF_TBAR     ((size_t)147456)
#define OFF_MI       ((size_t)151552)
#define OFF_P        ((size_t)155648)
#define OFF_VARPART  ((size_t)155712)   // 8192 slots (grid-sized)
#define OFF_LAM      ((size_t)163904)   // NB*ND: lg (stage2 phase) then sigma
#define OFF_TPART    ((size_t)688192)   // G2T*4096 per-block partials

#define G2T_BLOCKS 2048   // tangent-reduction grid (ws-limited)

// ---------------------------------------------------------------------------
__device__ __forceinline__ float bperm_f(int pa, float x) {
  return __builtin_bit_cast(float,
      __builtin_amdgcn_ds_bpermute(pa, __builtin_bit_cast(int, x)));
}

// ---------------------------------------------------------------------------
// One-sided Jacobi, single wave per matrix, lane = column, w[64] = own column.
// Runtime XOR-tournament loop, ds_bpermute exchange with asm-pinned results
// (no remat double-issue). Wave-synchronous, no barriers. Returns ||w||^2.
// __launch_bounds__(64,2) gives a 256-arch-VGPR budget so w[64]+v[65] live in
// arch VGPRs -- (64,3)'s 170-reg budget pushed ~65 values into AGPRs and every
// access paid a v_accvgpr move (round-10: VALU-bound at 42% DS util).
// ---------------------------------------------------------------------------
__device__ float jacobi1s64(float (&w)[ND], int lane) {
  float a0 = 0.f, a1 = 0.f, a2 = 0.f, a3 = 0.f;
#pragma unroll
  for (int i = 0; i < ND; i += 4) {
    a0 = fmaf(w[i + 0], w[i + 0], a0);
    a1 = fmaf(w[i + 1], w[i + 1], a1);
    a2 = fmaf(w[i + 2], w[i + 2], a2);
    a3 = fmaf(w[i + 3], w[i + 3], a3);
  }
  float g = (a0 + a1) + (a2 + a3);

  for (int sweep = 0; sweep < 18; ++sweep) {
    bool any = false;
    for (int r = 1; r < ND; ++r) {
      int pa = (lane ^ r) << 2;
      float v[ND + 1];  // v[64] = partner's g
#pragma unroll
      for (int i = 0; i <= ND; ++i) {
        float t = bperm_f(pa, (i < ND) ? w[i] : g);
        asm volatile("" : "+v"(t));  // pin: keep live, never re-issue
        v[i] = t;
      }
      float gv = v[ND];
      float b0 = 0.f, b1 = 0.f, b2 = 0.f, b3 = 0.f;
#pragma unroll
      for (int i = 0; i < ND; i += 4) {
        b0 = fmaf(w[i + 0], v[i + 0], b0);
        b1 = fmaf(w[i + 1], v[i + 1], b1);
        b2 = fmaf(w[i + 2], v[i + 2], b2);
        b3 = fmaf(w[i + 3], v[i + 3], b3);
      }
      float apq = (b0 + b1) + (b2 + b3);
      if (apq * apq > 4e-10f * g * gv) {
        int partner = lane ^ r;
        bool amP = lane < partner;
        float app = amP ? g : gv;
        float aqq = amP ? gv : g;
        float tau = (aqq - app) / (2.f * apq);
        float t = 1.f / (fabsf(tau) + sqrtf(1.f + tau * tau));
        t = (tau < 0.f) ? -t : t;
        float c = 1.f / sqrtf(1.f + t * t);
        float s = t * c;
        float s2v = amP ? -s : s;
#pragma unroll
        for (int i = 0; i < ND; ++i) w[i] = fmaf(s2v, v[i], c * w[i]);
        float d = t * apq;
        g = amP ? (g - d) : (g + d);
        any = true;
      }
    }
    if (!__any(any)) break;
  }
  a0 = a1 = a2 = a3 = 0.f;
#pragma unroll
  for (int i = 0; i < ND; i += 4) {
    a0 = fmaf(w[i + 0], w[i + 0], a0);
    a1 = fmaf(w[i + 1], w[i + 1], a1);
    a2 = fmaf(w[i + 2], w[i + 2], a2);
    a3 = fmaf(w[i + 3], w[i + 3], a3);
  }
  return (a0 + a1) + (a2 + a3);
}

// ---------------------------------------------------------------------------
// Wave-private congruence M = q*(x*q), q symmetric; lane = column of M.
// Two-pass staging of x (32 rows at a time, chunk-swizzled) into an 8KB
// wave-private LDS buffer; B in regs; step2 via half-parking B.
// ---------------------------------------------------------------------------
__device__ __forceinline__ void congruence2(const float* __restrict__ xi,
                                            const float* __restrict__ q,
                                            float* __restrict__ XL, int lane,
                                            float (&w)[ND]) {
  float B[ND];
#pragma unroll
  for (int i = 0; i < ND; ++i) B[i] = 0.f;

  const float* qc = q + lane * ND;  // q[a][lane] = q[lane][a] (symmetric)
  for (int p = 0; p < 2; ++p) {
#pragma unroll
    for (int k = 0; k < 8; ++k) {
      int m = k * 64 + lane;
      float4 rv = ((const float4*)(xi + p * 2048))[m];
      int phys = m ^ ((m >> 4) & 7);
      ((float4*)XL)[phys] = rv;
    }
    for (int a0 = 0; a0 < 32; ++a0) {
      int a = p * 32 + a0;
      float sa = qc[a];
      int base = a0 * 16, sw = a0 & 7;
#pragma unroll
      for (int k = 0; k < 16; ++k) {
        const float4 c4 = ((const float4*)XL)[base + (k ^ sw)];
        B[4 * k + 0] = fmaf(c4.x, sa, B[4 * k + 0]);
        B[4 * k + 1] = fmaf(c4.y, sa, B[4 * k + 1]);
        B[4 * k + 2] = fmaf(c4.z, sa, B[4 * k + 2]);
        B[4 * k + 3] = fmaf(c4.w, sa, B[4 * k + 3]);
      }
    }
  }
#pragma unroll
  for (int i = 0; i < ND; ++i) w[i] = 0.f;
  for (int h = 0; h < 2; ++h) {
#pragma unroll
    for (int j = 0; j < 32; ++j) XL[j * ND + lane] = B[h * 32 + j];
    for (int a0 = 0; a0 < 32; ++a0) {
      float ba = XL[a0 * ND + lane];
      const float* qr = q + (h * 32 + a0) * ND;  // row (uniform -> s_load)
#pragma unroll
      for (int r = 0; r < ND; ++r) w[r] = fmaf(qr[r], ba, w[r]);
    }
  }
}

// ---------------------------------------------------------------------------
// Two-sided LDS Jacobi (256 threads, one 64x64 matrix) for the few singles.
// ---------------------------------------------------------------------------
__device__ void jacobi2s(float (&A)[ND][PAD], float (&V)[ND][PAD], int tid) {
  __shared__ float cs_[32], sn_[32];
  __shared__ int   pp_[32], qq_[32];
  __shared__ int   rotcnt_;
  __shared__ float fro2_;
  __shared__ float red_[4];

  __syncthreads();
  float loc = 0.f;
  for (int e = tid; e < NN; e += 256) { float a = A[e >> 6][e & 63]; loc += a * a; }
  for (int o = 32; o; o >>= 1) loc += __shfl_down(loc, o);
  if ((tid & 63) == 0) red_[tid >> 6] = loc;
  __syncthreads();
  if (tid == 0) fro2_ = red_[0] + red_[1] + red_[2] + red_[3];
  __syncthreads();
  float fro2 = fro2_;

  for (int sweep = 0; sweep < 20; ++sweep) {
    if (tid == 0) rotcnt_ = 0;
    __syncthreads();
    for (int r = 0; r < 63; ++r) {
      if (tid < 32) {
        int p, q;
        if (tid == 0) { p = 63; q = r; }
        else { p = (r + tid) % 63; q = (r + 63 - tid) % 63; }
        if (p > q) { int t0 = p; p = q; q = t0; }
        pp_[tid] = p; qq_[tid] = q;
        float app = A[p][p], aqq = A[q][q], apq = A[p][q];
        float thr = fmaxf(1e-12f * fabsf(app * aqq), 1e-14f * fro2);
        float c = 1.f, s = 0.f;
        if (apq * apq > thr) {
          float tau = (aqq - app) / (2.f * apq);
          float t = 1.f / (fabsf(tau) + sqrtf(1.f + tau * tau));
          t = (tau < 0.f) ? -t : t;
          c = 1.f / sqrtf(1.f + t * t);
          s = t * c;
          atomicAdd(&rotcnt_, 1);
        }
        cs_[tid] = c; sn_[tid] = s;
      }
      __syncthreads();
      for (int t = tid; t < 2048; t += 256) {
        int k = t >> 6, j = t & 63;
        int p = pp_[k], q = qq_[k]; float c = cs_[k], s = sn_[k];
        float ap = A[p][j], aq = A[q][j];
        A[p][j] = c * ap - s * aq;
        A[q][j] = s * ap + c * aq;
      }
      __syncthreads();
      for (int t = tid; t < 4096; t += 256) {
        int k = (t >> 6) & 31, j = t & 63;
        int p = pp_[k], q = qq_[k]; float c = cs_[k], s = sn_[k];
        if (t < 2048) {
          float ap = A[j][p], aq = A[j][q];
          A[j][p] = c * ap - s * aq;
          A[j][q] = s * ap + c * aq;
        } else {
          float vp = V[j][p], vq = V[j][q];
          V[j][p] = c * vp - s * vq;
          V[j][q] = s * vp + c * vq;
        }
      }
      __syncthreads();
    }
    int rc = rotcnt_;
    __syncthreads();
    if (rc == 0) break;
  }
}

__device__ void recon_write(const float (&V)[ND][PAD], const float* f, float* g,
                            int c, int wq) {
  float acc[16];
#pragma unroll
  for (int k = 0; k < 16; ++k) acc[k] = 0.f;
  for (int j = 0; j < ND; ++j) {
    float m = f[j] * V[c][j];
#pragma unroll
    for (int k = 0; k < 16; ++k) acc[k] = fmaf(V[wq + 4 * k][j], m, acc[k]);
  }
#pragma unroll
  for (int k = 0; k < 16; ++k) g[(wq + 4 * k) * ND + c] = acc[k];
}

// ---------------------------------------------------------------------------
// Kernels
// ---------------------------------------------------------------------------
__global__ __launch_bounds__(256) void k_mean_part(const float* __restrict__ x,
                                                   float* __restrict__ part) {
  int e = blockIdx.x * 256 + threadIdx.x;
  int chunk = blockIdx.y;
  const float* px = x + (size_t)chunk * 256 * NN + e;
  float s = 0.f;
  for (int i = 0; i < 256; ++i) s += px[(size_t)i * NN];
  part[(size_t)chunk * NN + e] = s;
}

__global__ __launch_bounds__(256) void k_mean_final(const float* __restrict__ part,
                                                    float* __restrict__ meanA) {
  int e = blockIdx.x * 256 + threadIdx.x;
  float s = 0.f;
  for (int c = 0; c < 32; ++c) s += part[(size_t)c * NN + e];
  meanA[e] = s * (1.f / (float)NB);
}

__global__ __launch_bounds__(256) void k_prep1(const float* __restrict__ meanA,
                                               const float* __restrict__ shift,
                                               float* __restrict__ s_out,
                                               float* __restrict__ si_out,
                                               float* __restrict__ ss_out) {
  __shared__ float A[ND][PAD], V[ND][PAD];
  __shared__ float f1[ND], f2[ND];
  int tid = threadIdx.x;
  const float* src = (blockIdx.x == 0) ? meanA : shift;
  for (int e = tid; e < NN; e += 256) A[e >> 6][e & 63] = src[e];
  for (int e = tid; e < NN; e += 256) V[e >> 6][e & 63] = ((e >> 6) == (e & 63)) ? 1.f : 0.f;
  jacobi2s(A, V, tid);
  if (tid < ND) {
    float wv = fmaxf(A[tid][tid], 1e-30f);
    f1[tid] = sqrtf(wv);
    f2[tid] = 1.f / sqrtf(wv);
  }
  __syncthreads();
  int c = tid & 63, wq = tid >> 6;
  if (blockIdx.x == 0) {
    recon_write(V, f1, s_out, c, wq);
    recon_write(V, f2, si_out, c, wq);
  } else {
    recon_write(V, f1, ss_out, c, wq);
  }
}

// jacobi-only: M = si*x_i*si eigh -> write U^T (row j = u_j) and log(lambda).
// ONE matrix per block; grid = NB (32 blocks/CU queued -> DS-pipe saturation).
__global__ __launch_bounds__(64, 2) void k_stage2jac(const float* __restrict__ x,
                                                     const float* __restrict__ si,
                                                     float* __restrict__ uout,
                                                     float* __restrict__ lgout) {
  __shared__ float XL[2048];
  int lane = threadIdx.x;
  int i = blockIdx.x;
  float w[ND];
  congruence2(x + (size_t)i * NN, si, XL, lane, w);
  float s2 = jacobi1s64(w, lane);
  float sig = sqrtf(fmaxf(s2, 1e-38f));
  float inv = 1.f / sig;
  lgout[(size_t)i * ND + lane] = logf(sig);
#pragma unroll
  for (int g2 = 0; g2 < 16; ++g2) {
    float4 u4 = make_float4(w[4 * g2 + 0] * inv, w[4 * g2 + 1] * inv,
                            w[4 * g2 + 2] * inv, w[4 * g2 + 3] * inv);
    *(float4*)(uout + (size_t)i * NN + lane * ND + g2 * 4) = u4;
  }
}

// tangent partials: t[r][c] = sum_j lg[j] * Ut[j][r] * Ut[j][c]
__global__ __launch_bounds__(256) void k_tangent(const float* __restrict__ uin,
                                                 const float* __restrict__ lg,
                                                 float* __restrict__ tPart,
                                                 int G2) {
  __shared__ float Ut[ND][PAD];
  __shared__ float lw[ND];
  int tid = threadIdx.x;
  int c = tid & 63, wq = tid >> 6;
  float acc[16];
#pragma unroll
  for (int k = 0; k < 16; ++k) acc[k] = 0.f;

  for (int i = blockIdx.x; i < NB; i += G2) {
    __syncthreads();
    for (int e = tid; e < NN; e += 256) Ut[e >> 6][e & 63] = uin[(size_t)i * NN + e];
    if (tid < ND) lw[tid] = lg[(size_t)i * ND + tid];
    __syncthreads();
    for (int j = 0; j < ND; ++j) {
      float m = lw[j] * Ut[j][c];
#pragma unroll
      for (int k = 0; k < 16; ++k) acc[k] = fmaf(Ut[j][wq + 4 * k], m, acc[k]);
    }
  }
#pragma unroll
  for (int k = 0; k < 16; ++k)
    tPart[(size_t)blockIdx.x * NN + (wq + 4 * k) * ND + c] = acc[k];
}

__global__ __launch_bounds__(256) void k_reduce_t(const float* __restrict__ tPart,
                                                  float* __restrict__ tbar, int nw) {
  int e = blockIdx.x * 256 + threadIdx.x;
  float s = 0.f;
  for (int b = 0; b < nw; ++b) s += tPart[(size_t)b * NN + e];
  tbar[e] = s * (1.f / (float)NB);
}

__global__ __launch_bounds__(256) void k_prep2(const float* __restrict__ tbar,
                                               const float* __restrict__ s_g,
                                               float* __restrict__ mi_out) {
  __shared__ float A[ND][PAD], V[ND][PAD];
  __shared__ float f1[ND];
  int tid = threadIdx.x;
  int c = tid & 63, wq = tid >> 6;
  for (int e = tid; e < NN; e += 256) A[e >> 6][e & 63] = tbar[e];
  for (int e = tid; e < NN; e += 256) V[e >> 6][e & 63] = ((e >> 6) == (e & 63)) ? 1.f : 0.f;
  jacobi2s(A, V, tid);
  if (tid < ND) f1[tid] = expf(A[tid][tid]);
  __syncthreads();
  {
    float acc[16];
#pragma unroll
    for (int k = 0; k < 16; ++k) acc[k] = 0.f;
    for (int j = 0; j < ND; ++j) {
      float m = f1[j] * V[c][j];
#pragma unroll
      for (int k = 0; k < 16; ++k) acc[k] = fmaf(V[wq + 4 * k][j], m, acc[k]);
    }
    __syncthreads();
#pragma unroll
    for (int k = 0; k < 16; ++k) A[wq + 4 * k][c] = acc[k];
  }
  __syncthreads();
  {
    float acc[16];
#pragma unroll
    for (int k = 0; k < 16; ++k) acc[k] = 0.f;
    for (int a = 0; a < ND; ++a) {
      float ea = A[a][c];
#pragma unroll
      for (int k = 0; k < 16; ++k) acc[k] = fmaf(s_g[(wq + 4 * k) * ND + a], ea, acc[k]);
    }
    __syncthreads();
#pragma unroll
    for (int k = 0; k < 16; ++k) V[wq + 4 * k][c] = acc[k];
  }
  __syncthreads();
  {
    float acc[16];
#pragma unroll
    for (int k = 0; k < 16; ++k) acc[k] = 0.f;
    for (int a = 0; a < ND; ++a) {
      float sa = s_g[a * ND + c];
#pragma unroll
      for (int k = 0; k < 16; ++k) acc[k] = fmaf(V[wq + 4 * k][a], sa, acc[k]);
    }
    __syncthreads();
#pragma unroll
    for (int k = 0; k < 16; ++k) A[wq + 4 * k][c] = acc[k];
  }
  __syncthreads();
  for (int e = tid; e < NN; e += 256) V[e >> 6][e & 63] = ((e >> 6) == (e & 63)) ? 1.f : 0.f;
  jacobi2s(A, V, tid);
  if (tid < ND) f1[tid] = 1.f / sqrtf(fmaxf(A[tid][tid], 1e-30f));
  __syncthreads();
  recon_write(V, f1, mi_out, c, wq);
}

// jacobi-only: M = mi*x_i*mi eigh -> write U^T, sigma, var partials.
__global__ __launch_bounds__(64, 2) void k_stage3jac(const float* __restrict__ x,
                                                     const float* __restrict__ mi,
                                                     float* __restrict__ uout,
                                                     float* __restrict__ lam,
                                                     float* __restrict__ varPart) {
  __shared__ float XL[2048];
  int lane = threadIdx.x;
  int i = blockIdx.x;
  float w[ND];
  congruence2(x + (size_t)i * NN, mi, XL, lane, w);
  float s2 = jacobi1s64(w, lane);
  float sig = sqrtf(fmaxf(s2, 1e-38f));
  float inv = 1.f / sig;
  lam[(size_t)i * ND + lane] = sig;
  float lg = logf(sig);
  float varacc = lg * lg;
#pragma unroll
  for (int g2 = 0; g2 < 16; ++g2) {
    float4 u4 = make_float4(w[4 * g2 + 0] * inv, w[4 * g2 + 1] * inv,
                            w[4 * g2 + 2] * inv, w[4 * g2 + 3] * inv);
    *(float4*)(uout + (size_t)i * NN + lane * ND + g2 * 4) = u4;
  }
  for (int o = 32; o; o >>= 1) varacc += __shfl_down(varacc, o);
  if (lane == 0) varPart[i] = varacc;
}

__global__ __launch_bounds__(64) void k_pfinal(const float* __restrict__ varPart,
                                               const float* __restrict__ scale,
                                               float* __restrict__ pout, int n) {
  int tid = threadIdx.x;
  float s = 0.f;
  for (int i = tid; i < n; i += 64) s += varPart[i];
  for (int o = 32; o; o >>= 1) s += __shfl_down(s, o);
  if (tid == 0) {
    float var = s * (1.f / (float)NB);
    float sd = sqrtf(var);
    pout[0] = scale[0] / (sd + 1e-5f);
  }
}

// out_i = (ss*U_i) diag(lam^p) (ss*U_i)^T, U_i read as U^T rows from uin.
__global__ __launch_bounds__(256) void k_stage5(const float* __restrict__ uin,
                                                const float* __restrict__ ss,
                                                const float* __restrict__ lam,
                                                const float* __restrict__ pws,
                                                float* __restrict__ out) {
  __shared__ float Ut[ND][PAD];   // row j = u_j
  __shared__ float A2[ND][PAD];   // A = ss*U
  __shared__ float lp[ND];
  int tid = threadIdx.x;
  int i = blockIdx.x;
  for (int e = tid; e < NN; e += 256) Ut[e >> 6][e & 63] = uin[(size_t)i * NN + e];
  if (tid < ND) lp[tid] = powf(lam[(size_t)i * ND + tid], pws[0]);
  __syncthreads();
  int c = tid & 63, wq = tid >> 6;
  float acc[16];
#pragma unroll
  for (int k = 0; k < 16; ++k) acc[k] = 0.f;
  for (int a = 0; a < ND; ++a) {
    float ua = Ut[c][a];
    const float* ssr = ss + a * ND;
#pragma unroll
    for (int k = 0; k < 16; ++k) acc[k] = fmaf(ssr[wq + 4 * k], ua, acc[k]);
  }
#pragma unroll
  for (int k = 0; k < 16; ++k) A2[wq + 4 * k][c] = acc[k];
  __syncthreads();
  float o2[16];
#pragma unroll
  for (int k = 0; k < 16; ++k) o2[k] = 0.f;
  for (int j = 0; j < ND; ++j) {
    float m = lp[j] * A2[c][j];
#pragma unroll
    for (int k = 0; k < 16; ++k) o2[k] = fmaf(A2[wq + 4 * k][j], m, o2[k]);
  }
#pragma unroll
  for (int k = 0; k < 16; ++k)
    out[(size_t)i * NN + (wq + 4 * k) * ND + c] = o2[k];
}

// ---------------------------------------------------------------------------
extern "C" void kernel_launch(void* const* d_in, const int* in_sizes, int n_in,
                              void* d_out, int out_size, void* d_ws, size_t ws_size,
                              hipStream_t stream) {
  const float* x     = (const float*)d_in[0];
  const float* shift = (const float*)d_in[1];
  const float* scale = (const float*)d_in[2];
  float* out = (float*)d_out;
  float* ws  = (float*)d_ws;
  (void)in_sizes; (void)n_in; (void)out_size;

  size_t wsf = ws_size / 4;
  int G2T = G2T_BLOCKS;
  if (OFF_TPART + (size_t)G2T * NN > wsf) {
    size_t avail = (wsf > OFF_TPART) ? (wsf - OFF_TPART) / NN : 1;
    if (avail < 1) avail = 1;
    if (avail < (size_t)G2T) G2T = (int)avail;
  }

  k_mean_part<<<dim3(16, 32), 256, 0, stream>>>(x, ws + OFF_MEANPART);
  k_mean_final<<<16, 256, 0, stream>>>(ws + OFF_MEANPART, ws + OFF_MEANA);
  k_prep1<<<2, 256, 0, stream>>>(ws + OFF_MEANA, shift, ws + OFF_S, ws + OFF_SI,
                                 ws + OFF_SS);
  // phase A: eigh(si*x*si) -> U^T in d_out (scratch), lg in LAM
  k_stage2jac<<<NB, 64, 0, stream>>>(x, ws + OFF_SI, out, ws + OFF_LAM);
  k_tangent<<<G2T, 256, 0, stream>>>(out, ws + OFF_LAM, ws + OFF_TPART, G2T);
  k_reduce_t<<<16, 256, 0, stream>>>(ws + OFF_TPART, ws + OFF_TBAR, G2T);
  k_prep2<<<1, 256, 0, stream>>>(ws + OFF_TBAR, ws + OFF_S, ws + OFF_MI);
  // phase B: eigh(mi*x*mi) -> U^T in d_out, sigma in LAM, var partials
  k_stage3jac<<<NB, 64, 0, stream>>>(x, ws + OFF_MI, out, ws + OFF_LAM,
                                     ws + OFF_VARPART);
  k_pfinal<<<1, 64, 0, stream>>>(ws + OFF_VARPART, scale, ws + OFF_P, NB);
  // out_i = (ss*U_i) diag(lam^p) (ss*U_i)^T, in place over d_out
  k_stage5<<<8192, 256, 0, stream>>>(out, ws + OFF_SS, ws + OFF_LAM, ws + OFF_P,
                                     out);
}